// Round 1
// baseline (1378.183 us; speedup 1.0000x reference)
//
#include <hip/hip_runtime.h>
#include <hip/hip_bf16.h>
#include <math.h>

// ---------------- row_ptr: lower_bound per node over sorted edge_row ----------------
__global__ void rowptr_k(const int* __restrict__ erow, int* __restrict__ rp, int n, int e) {
    int i = blockIdx.x * blockDim.x + threadIdx.x;
    if (i > n) return;
    int lo = 0, hi = e;
    while (lo < hi) {
        int mid = (lo + hi) >> 1;
        if (erow[mid] < i) lo = mid + 1; else hi = mid;
    }
    rp[i] = lo;
}

__global__ void zero_k(float* __restrict__ p) {
    int i = threadIdx.x;
    if (i < 224) p[i] = 0.f;
}

__device__ __forceinline__ float elu_f(float t) {
    return t > 0.f ? t : expm1f(t);
}

// ---------------- tiled fp32 GEMM: out[N x NC] = act(X)[N x K] @ W[K x NC] ----------
// BN=true: apply y = x*scale[k]+shift[k], then ELU, to X elements while staging
// (scale/shift derived from batch sums in `stats`: [0..K)=sum, [K..2K)=sumsq).
template<int K, int NC, bool BN>
__global__ __launch_bounds__(256) void gemm_k(const float* __restrict__ X,
                                              const float* __restrict__ W,
                                              const float* __restrict__ stats,
                                              const float* __restrict__ gamma,
                                              const float* __restrict__ beta,
                                              float* __restrict__ out, int nrows) {
    constexpr int KT = (K < 64) ? K : 64;   // k-tile
    constexpr int S  = KT + 4;              // xs row stride (mult of 4 -> float4 aligned)
    __shared__ float xs[64 * S];
    __shared__ float ws[KT * NC];
    __shared__ float sc[KT];
    __shared__ float sh[KT];

    const int tid  = threadIdx.x;
    const int c    = tid & 63;
    const int rg   = tid >> 6;
    const int row0 = blockIdx.x * 64;

    if (BN) {
        if (tid < K) {
            float s1 = stats[tid], s2 = stats[K + tid];
            float mean = s1 / (float)nrows;
            float var  = s2 / (float)nrows - mean * mean;
            float rstd = rsqrtf(var + 1e-5f);
            float scl  = gamma[tid] * rstd;
            sc[tid] = scl;
            sh[tid] = beta[tid] - mean * scl;
        }
        __syncthreads();
    }

    float acc[16];
#pragma unroll
    for (int i = 0; i < 16; ++i) acc[i] = 0.f;

    for (int k0 = 0; k0 < K; k0 += KT) {
        // stage X tile (64 rows x KT), BN+ELU fused
        for (int idx = tid * 4; idx < 64 * KT; idx += 1024) {
            int r = idx / KT, k = idx - r * KT;
            int gr = row0 + r;
            float4 v = make_float4(0.f, 0.f, 0.f, 0.f);
            if (gr < nrows) v = *(const float4*)&X[(long)gr * K + k0 + k];
            if (BN) {
                v.x = elu_f(v.x * sc[k + 0] + sh[k + 0]);
                v.y = elu_f(v.y * sc[k + 1] + sh[k + 1]);
                v.z = elu_f(v.z * sc[k + 2] + sh[k + 2]);
                v.w = elu_f(v.w * sc[k + 3] + sh[k + 3]);
            }
            *(float4*)&xs[r * S + k] = v;
        }
        // stage W tile (KT x NC), contiguous
        for (int idx = tid * 4; idx < KT * NC; idx += 1024) {
            *(float4*)&ws[idx] = *(const float4*)&W[k0 * NC + idx];
        }
        __syncthreads();

        if (c < NC) {
            for (int kk = 0; kk < KT; kk += 4) {
                float w0 = ws[(kk + 0) * NC + c];
                float w1 = ws[(kk + 1) * NC + c];
                float w2 = ws[(kk + 2) * NC + c];
                float w3 = ws[(kk + 3) * NC + c];
#pragma unroll
                for (int i = 0; i < 16; ++i) {
                    const float4 xv = *(const float4*)&xs[(rg * 16 + i) * S + kk];
                    acc[i] += xv.x * w0 + xv.y * w1 + xv.z * w2 + xv.w * w3;
                }
            }
        }
        __syncthreads();
    }

    if (c < NC) {
#pragma unroll
        for (int i = 0; i < 16; ++i) {
            int gr = row0 + rg * 16 + i;
            if (gr < nrows) out[(long)gr * NC + c] = acc[i];
        }
    }
}

// ---------------- SpMM: out[i][c] = sum_{e in row i} val[e] * sup[col[e]][c] --------
template<int F>
__global__ __launch_bounds__(256) void spmm_k(const int* __restrict__ rp,
                                              const int* __restrict__ ecol,
                                              const float* __restrict__ ev,
                                              const float* __restrict__ sup,
                                              float* __restrict__ out, int n) {
    constexpr int NPW = 64 / F;  // nodes per wave
    const int lane = threadIdx.x & 63;
    const int wid  = (blockIdx.x * blockDim.x + threadIdx.x) >> 6;
    const int sub  = lane / F;
    const int c    = lane - sub * F;
    const int node = wid * NPW + sub;
    if (sub >= NPW || node >= n) return;
    const int s = rp[node], e = rp[node + 1];
    float acc = 0.f;
    for (int i = s; i < e; ++i) {
        int col  = ecol[i];
        float v  = ev[i];
        acc += v * sup[(long)col * F + c];
    }
    out[(long)node * F + c] = acc;
}

// ---------------- SpMM (F=40) + fused log_softmax --------------------------------
__global__ __launch_bounds__(256) void spmm4_k(const int* __restrict__ rp,
                                               const int* __restrict__ ecol,
                                               const float* __restrict__ ev,
                                               const float* __restrict__ sup,
                                               float* __restrict__ out, int n) {
    const int lane = threadIdx.x & 63;
    const int node = (blockIdx.x * blockDim.x + threadIdx.x) >> 6;
    const bool valid = (lane < 40) && (node < n);
    float acc = -INFINITY;
    if (valid) {
        const int s = rp[node], e = rp[node + 1];
        float a = 0.f;
        for (int i = s; i < e; ++i) {
            int col = ecol[i];
            float v = ev[i];
            a += v * sup[(long)col * 40 + lane];
        }
        acc = a;
    }
    float m = acc;
#pragma unroll
    for (int o = 32; o; o >>= 1) m = fmaxf(m, __shfl_xor(m, o, 64));
    float p = valid ? expf(acc - m) : 0.f;
    float ssum = p;
#pragma unroll
    for (int o = 32; o; o >>= 1) ssum += __shfl_xor(ssum, o, 64);
    if (valid) out[(long)node * 40 + lane] = acc - m - logf(ssum);
}

// ---------------- per-feature batch sums (for BN): stats[c]=sum, stats[F+c]=sumsq --
template<int F>
__global__ __launch_bounds__(256) void stats_k(const float* __restrict__ h,
                                               float* __restrict__ stats, int n) {
    __shared__ float sm1[256];
    __shared__ float sm2[256];
    const int tid = threadIdx.x;
    float s1 = 0.f, s2 = 0.f;
    const long total = (long)n * F;
    for (long idx = (long)blockIdx.x * 256 + tid; idx < total; idx += (long)gridDim.x * 256) {
        float v = h[idx];
        s1 += v;
        s2 += v * v;
    }
    sm1[tid] = s1;
    sm2[tid] = s2;
    __syncthreads();
    if (tid < F) {
#pragma unroll
        for (int j = 1; j < 256 / F; ++j) {
            s1 += sm1[tid + j * F];
            s2 += sm2[tid + j * F];
        }
        atomicAdd(&stats[tid], s1);
        atomicAdd(&stats[F + tid], s2);
    }
}

extern "C" void kernel_launch(void* const* d_in, const int* in_sizes, int n_in,
                              void* d_out, int out_size, void* d_ws, size_t ws_size,
                              hipStream_t stream) {
    const float* x    = (const float*)d_in[0];
    const int*   erow = (const int*)d_in[1];
    const int*   ecol = (const int*)d_in[2];
    const float* ev   = (const float*)d_in[3];
    const float* W1   = (const float*)d_in[4];
    const float* W2   = (const float*)d_in[5];
    const float* W3   = (const float*)d_in[6];
    const float* W4   = (const float*)d_in[7];
    const float* g1   = (const float*)d_in[8];
    const float* b1   = (const float*)d_in[9];
    const float* g2   = (const float*)d_in[10];
    const float* b2   = (const float*)d_in[11];
    const float* g3   = (const float*)d_in[12];
    const float* b3   = (const float*)d_in[13];

    const int N = in_sizes[0] / 512;
    const int E = in_sizes[1];

    // workspace layout: row_ptr | stats(224f, 256 reserved) | A (N*64) | B (N*64)
    char* w = (char*)d_ws;
    int* rp = (int*)w;
    size_t off = (((size_t)(N + 1) * 4) + 255) & ~(size_t)255;
    float* stats = (float*)(w + off);
    float* A = stats + 256;
    float* B = A + (size_t)N * 64;
    float* outp = (float*)d_out;

    const int gblocks = (N + 63) / 64;

    rowptr_k<<<(N + 1 + 255) / 256, 256, 0, stream>>>(erow, rp, N, E);
    zero_k<<<1, 256, 0, stream>>>(stats);

    // layer 1: support = x @ W1 ; h1 = SpMM(support)
    gemm_k<512, 64, false><<<gblocks, 256, 0, stream>>>(x, W1, nullptr, nullptr, nullptr, A, N);
    spmm_k<64><<<(N + 3) / 4, 256, 0, stream>>>(rp, ecol, ev, A, B, N);
    stats_k<64><<<512, 256, 0, stream>>>(B, stats, N);

    // layer 2: support = bn_elu(h1) @ W2 ; h2 = SpMM(support)
    gemm_k<64, 32, true><<<gblocks, 256, 0, stream>>>(B, W2, stats, g1, b1, A, N);
    {
        int waves = (N + 1) / 2;
        spmm_k<32><<<(waves + 3) / 4, 256, 0, stream>>>(rp, ecol, ev, A, B, N);
    }
    stats_k<32><<<512, 256, 0, stream>>>(B, stats + 128, N);

    // layer 3
    gemm_k<32, 16, true><<<gblocks, 256, 0, stream>>>(B, W3, stats + 128, g2, b2, A, N);
    {
        int waves = (N + 3) / 4;
        spmm_k<16><<<(waves + 3) / 4, 256, 0, stream>>>(rp, ecol, ev, A, B, N);
    }
    stats_k<16><<<512, 256, 0, stream>>>(B, stats + 192, N);

    // layer 4 + fused log_softmax
    gemm_k<16, 40, true><<<gblocks, 256, 0, stream>>>(B, W4, stats + 192, g3, b3, A, N);
    spmm4_k<<<(N + 3) / 4, 256, 0, stream>>>(rp, ecol, ev, A, outp, N);
}

// Round 2
// 843.962 us; speedup vs baseline: 1.6330x; 1.6330x over previous
//
#include <hip/hip_runtime.h>
#include <hip/hip_bf16.h>
#include <math.h>

// ---------------- row_ptr: lower_bound per node over sorted edge_row ----------------
__global__ void rowptr_k(const int* __restrict__ erow, int* __restrict__ rp, int n, int e) {
    int i = blockIdx.x * blockDim.x + threadIdx.x;
    if (i > n) return;
    int lo = 0, hi = e;
    while (lo < hi) {
        int mid = (lo + hi) >> 1;
        if (erow[mid] < i) lo = mid + 1; else hi = mid;
    }
    rp[i] = lo;
}

__global__ void zero_k(float* __restrict__ p) {
    int i = threadIdx.x;
    if (i < 224) p[i] = 0.f;
}

__device__ __forceinline__ float elu_f(float t) {
    return t > 0.f ? t : expm1f(t);
}

// ---------------- GEMM1: out[N x 64] = X[N x 512] @ W[512 x 64], 4x4 register tile --
__global__ __launch_bounds__(256) void gemm1_k(const float* __restrict__ X,
                                               const float* __restrict__ W,
                                               float* __restrict__ out, int nrows) {
    constexpr int KT = 64, S = KT + 4;  // xs row stride 68 floats (float4-aligned)
    __shared__ float xs[64 * S];
    __shared__ float ws[KT * 64];

    const int tid  = threadIdx.x;
    const int cg   = tid & 15;   // cols cg*4 .. cg*4+3
    const int rgr  = tid >> 4;   // rows rgr*4 .. rgr*4+3
    const int row0 = blockIdx.x * 64;

    float4 a[4];
#pragma unroll
    for (int r = 0; r < 4; ++r) a[r] = make_float4(0.f, 0.f, 0.f, 0.f);

    for (int k0 = 0; k0 < 512; k0 += KT) {
        // stage X tile: 64 rows x 64 k
#pragma unroll
        for (int idx = tid * 4; idx < 64 * KT; idx += 1024) {
            int r = idx >> 6, k = idx & 63;
            int gr = row0 + r;
            float4 v = make_float4(0.f, 0.f, 0.f, 0.f);
            if (gr < nrows) v = *(const float4*)&X[(long)gr * 512 + k0 + k];
            *(float4*)&xs[r * S + k] = v;
        }
        // stage W tile: contiguous KT*64 floats
#pragma unroll
        for (int idx = tid * 4; idx < KT * 64; idx += 1024) {
            *(float4*)&ws[idx] = *(const float4*)&W[k0 * 64 + idx];
        }
        __syncthreads();

#pragma unroll
        for (int kk = 0; kk < KT; kk += 4) {
            float4 xv[4], wv[4];
#pragma unroll
            for (int r = 0; r < 4; ++r) xv[r] = *(const float4*)&xs[(rgr * 4 + r) * S + kk];
#pragma unroll
            for (int j = 0; j < 4; ++j) wv[j] = *(const float4*)&ws[(kk + j) * 64 + cg * 4];
#pragma unroll
            for (int j = 0; j < 4; ++j) {
                float4 w = wv[j];
#pragma unroll
                for (int r = 0; r < 4; ++r) {
                    float xx = ((const float*)&xv[r])[j];
                    a[r].x += xx * w.x;
                    a[r].y += xx * w.y;
                    a[r].z += xx * w.z;
                    a[r].w += xx * w.w;
                }
            }
        }
        __syncthreads();
    }

#pragma unroll
    for (int r = 0; r < 4; ++r) {
        int gr = row0 + rgr * 4 + r;
        if (gr < nrows) *(float4*)&out[(long)gr * 64 + cg * 4] = a[r];
    }
}

// ---------------- small tiled fp32 GEMM with fused BN+ELU on input ------------------
template<int K, int NC, bool BN>
__global__ __launch_bounds__(256) void gemm_k(const float* __restrict__ X,
                                              const float* __restrict__ W,
                                              const float* __restrict__ stats,
                                              const float* __restrict__ gamma,
                                              const float* __restrict__ beta,
                                              float* __restrict__ out, int nrows) {
    constexpr int KT = (K < 64) ? K : 64;
    constexpr int S  = KT + 4;
    __shared__ float xs[64 * S];
    __shared__ float ws[KT * NC];
    __shared__ float sc[KT];
    __shared__ float sh[KT];

    const int tid  = threadIdx.x;
    const int c    = tid & 63;
    const int rg   = tid >> 6;
    const int row0 = blockIdx.x * 64;

    if (BN) {
        if (tid < K) {
            float s1 = stats[tid], s2 = stats[K + tid];
            float mean = s1 / (float)nrows;
            float var  = s2 / (float)nrows - mean * mean;
            float rstd = rsqrtf(var + 1e-5f);
            float scl  = gamma[tid] * rstd;
            sc[tid] = scl;
            sh[tid] = beta[tid] - mean * scl;
        }
        __syncthreads();
    }

    float acc[16];
#pragma unroll
    for (int i = 0; i < 16; ++i) acc[i] = 0.f;

    for (int k0 = 0; k0 < K; k0 += KT) {
        for (int idx = tid * 4; idx < 64 * KT; idx += 1024) {
            int r = idx / KT, k = idx - r * KT;
            int gr = row0 + r;
            float4 v = make_float4(0.f, 0.f, 0.f, 0.f);
            if (gr < nrows) v = *(const float4*)&X[(long)gr * K + k0 + k];
            if (BN) {
                v.x = elu_f(v.x * sc[k + 0] + sh[k + 0]);
                v.y = elu_f(v.y * sc[k + 1] + sh[k + 1]);
                v.z = elu_f(v.z * sc[k + 2] + sh[k + 2]);
                v.w = elu_f(v.w * sc[k + 3] + sh[k + 3]);
            }
            *(float4*)&xs[r * S + k] = v;
        }
        for (int idx = tid * 4; idx < KT * NC; idx += 1024) {
            *(float4*)&ws[idx] = *(const float4*)&W[k0 * NC + idx];
        }
        __syncthreads();

        if (c < NC) {
            for (int kk = 0; kk < KT; kk += 4) {
                float w0 = ws[(kk + 0) * NC + c];
                float w1 = ws[(kk + 1) * NC + c];
                float w2 = ws[(kk + 2) * NC + c];
                float w3 = ws[(kk + 3) * NC + c];
#pragma unroll
                for (int i = 0; i < 16; ++i) {
                    const float4 xv = *(const float4*)&xs[(rg * 16 + i) * S + kk];
                    acc[i] += xv.x * w0 + xv.y * w1 + xv.z * w2 + xv.w * w3;
                }
            }
        }
        __syncthreads();
    }

    if (c < NC) {
#pragma unroll
        for (int i = 0; i < 16; ++i) {
            int gr = row0 + rg * 16 + i;
            if (gr < nrows) out[(long)gr * NC + c] = acc[i];
        }
    }
}

// ---------------- SpMM: out[i][c] = sum_{e in row i} val[e] * sup[col[e]][c] --------
// Unrolled x8: 8 independent gathers in flight per (sub)wave. For NPW==1 the node
// (and thus s,e and edge indices) is wave-uniform -> readfirstlane makes the
// col/val loads scalar (s_load) and gathers saddr-based.
template<int F>
__global__ __launch_bounds__(256) void spmm_k(const int* __restrict__ rp,
                                              const int* __restrict__ ecol,
                                              const float* __restrict__ ev,
                                              const float* __restrict__ sup,
                                              float* __restrict__ out, int n) {
    constexpr int NPW = 64 / F;  // nodes per wave
    const int lane = threadIdx.x & 63;
    const int wid  = (blockIdx.x * blockDim.x + threadIdx.x) >> 6;
    const int sub  = lane / F;
    const int c    = lane - sub * F;
    const int node = wid * NPW + sub;
    if (node >= n) return;
    int s = rp[node], e = rp[node + 1];
    if (NPW == 1) {
        s = __builtin_amdgcn_readfirstlane(s);
        e = __builtin_amdgcn_readfirstlane(e);
    }
    const float* __restrict__ supc = sup + c;
    float a0 = 0.f, a1 = 0.f, a2 = 0.f, a3 = 0.f;
    int i = s;
    for (; i + 8 <= e; i += 8) {
        int   k0 = ecol[i + 0], k1 = ecol[i + 1], k2 = ecol[i + 2], k3 = ecol[i + 3];
        int   k4 = ecol[i + 4], k5 = ecol[i + 5], k6 = ecol[i + 6], k7 = ecol[i + 7];
        float v0 = ev[i + 0], v1 = ev[i + 1], v2 = ev[i + 2], v3 = ev[i + 3];
        float v4 = ev[i + 4], v5 = ev[i + 5], v6 = ev[i + 6], v7 = ev[i + 7];
        float g0 = supc[(long)k0 * F], g1 = supc[(long)k1 * F];
        float g2 = supc[(long)k2 * F], g3 = supc[(long)k3 * F];
        float g4 = supc[(long)k4 * F], g5 = supc[(long)k5 * F];
        float g6 = supc[(long)k6 * F], g7 = supc[(long)k7 * F];
        a0 += v0 * g0; a1 += v1 * g1; a2 += v2 * g2; a3 += v3 * g3;
        a0 += v4 * g4; a1 += v5 * g5; a2 += v6 * g6; a3 += v7 * g7;
    }
    for (; i < e; ++i) a0 += ev[i] * supc[(long)ecol[i] * F];
    out[(long)node * F + c] = (a0 + a1) + (a2 + a3);
}

// ---------------- SpMM (F=40) + fused log_softmax -----------------------------------
__global__ __launch_bounds__(256) void spmm4_k(const int* __restrict__ rp,
                                               const int* __restrict__ ecol,
                                               const float* __restrict__ ev,
                                               const float* __restrict__ sup,
                                               float* __restrict__ out, int n) {
    const int lane = threadIdx.x & 63;
    const int node = (blockIdx.x * blockDim.x + threadIdx.x) >> 6;
    const bool valid = (lane < 40) && (node < n);
    float acc = -INFINITY;
    if (node < n) {
        int s = rp[node], e = rp[node + 1];
        s = __builtin_amdgcn_readfirstlane(s);
        e = __builtin_amdgcn_readfirstlane(e);
        if (lane < 40) {
            const float* __restrict__ supc = sup + lane;
            float a0 = 0.f, a1 = 0.f, a2 = 0.f, a3 = 0.f;
            int i = s;
            for (; i + 8 <= e; i += 8) {
                int   k0 = ecol[i + 0], k1 = ecol[i + 1], k2 = ecol[i + 2], k3 = ecol[i + 3];
                int   k4 = ecol[i + 4], k5 = ecol[i + 5], k6 = ecol[i + 6], k7 = ecol[i + 7];
                float v0 = ev[i + 0], v1 = ev[i + 1], v2 = ev[i + 2], v3 = ev[i + 3];
                float v4 = ev[i + 4], v5 = ev[i + 5], v6 = ev[i + 6], v7 = ev[i + 7];
                float g0 = supc[(long)k0 * 40], g1 = supc[(long)k1 * 40];
                float g2 = supc[(long)k2 * 40], g3 = supc[(long)k3 * 40];
                float g4 = supc[(long)k4 * 40], g5 = supc[(long)k5 * 40];
                float g6 = supc[(long)k6 * 40], g7 = supc[(long)k7 * 40];
                a0 += v0 * g0; a1 += v1 * g1; a2 += v2 * g2; a3 += v3 * g3;
                a0 += v4 * g4; a1 += v5 * g5; a2 += v6 * g6; a3 += v7 * g7;
            }
            for (; i < e; ++i) a0 += ev[i] * supc[(long)ecol[i] * 40];
            acc = (a0 + a1) + (a2 + a3);
        }
    }
    float m = acc;
#pragma unroll
    for (int o = 32; o; o >>= 1) m = fmaxf(m, __shfl_xor(m, o, 64));
    float p = valid ? expf(acc - m) : 0.f;
    float ssum = p;
#pragma unroll
    for (int o = 32; o; o >>= 1) ssum += __shfl_xor(ssum, o, 64);
    if (valid) out[(long)node * 40 + lane] = acc - m - logf(ssum);
}

// ---------------- per-feature batch sums (for BN): stats[c]=sum, stats[F+c]=sumsq ---
template<int F>
__global__ __launch_bounds__(256) void stats_k(const float* __restrict__ h,
                                               float* __restrict__ stats, int n) {
    __shared__ float sm1[256];
    __shared__ float sm2[256];
    const int tid = threadIdx.x;
    float s1 = 0.f, s2 = 0.f;
    const long total = (long)n * F;
    for (long idx = (long)blockIdx.x * 256 + tid; idx < total; idx += (long)gridDim.x * 256) {
        float v = h[idx];
        s1 += v;
        s2 += v * v;
    }
    sm1[tid] = s1;
    sm2[tid] = s2;
    __syncthreads();
    if (tid < F) {
#pragma unroll
        for (int j = 1; j < 256 / F; ++j) {
            s1 += sm1[tid + j * F];
            s2 += sm2[tid + j * F];
        }
        atomicAdd(&stats[tid], s1);
        atomicAdd(&stats[F + tid], s2);
    }
}

extern "C" void kernel_launch(void* const* d_in, const int* in_sizes, int n_in,
                              void* d_out, int out_size, void* d_ws, size_t ws_size,
                              hipStream_t stream) {
    const float* x    = (const float*)d_in[0];
    const int*   erow = (const int*)d_in[1];
    const int*   ecol = (const int*)d_in[2];
    const float* ev   = (const float*)d_in[3];
    const float* W1   = (const float*)d_in[4];
    const float* W2   = (const float*)d_in[5];
    const float* W3   = (const float*)d_in[6];
    const float* W4   = (const float*)d_in[7];
    const float* g1   = (const float*)d_in[8];
    const float* b1   = (const float*)d_in[9];
    const float* g2   = (const float*)d_in[10];
    const float* b2   = (const float*)d_in[11];
    const float* g3   = (const float*)d_in[12];
    const float* b3   = (const float*)d_in[13];

    const int N = in_sizes[0] / 512;
    const int E = in_sizes[1];

    // workspace layout: row_ptr | stats(224f, 256 reserved) | A (N*64) | B (N*64)
    char* w = (char*)d_ws;
    int* rp = (int*)w;
    size_t off = (((size_t)(N + 1) * 4) + 255) & ~(size_t)255;
    float* stats = (float*)(w + off);
    float* A = stats + 256;
    float* B = A + (size_t)N * 64;
    float* outp = (float*)d_out;

    const int gblocks = (N + 63) / 64;

    rowptr_k<<<(N + 1 + 255) / 256, 256, 0, stream>>>(erow, rp, N, E);
    zero_k<<<1, 256, 0, stream>>>(stats);

    // layer 1: support = x @ W1 ; h1 = SpMM(support)
    gemm1_k<<<gblocks, 256, 0, stream>>>(x, W1, A, N);
    spmm_k<64><<<(N + 3) / 4, 256, 0, stream>>>(rp, ecol, ev, A, B, N);
    stats_k<64><<<512, 256, 0, stream>>>(B, stats, N);

    // layer 2: support = bn_elu(h1) @ W2 ; h2 = SpMM(support)
    gemm_k<64, 32, true><<<gblocks, 256, 0, stream>>>(B, W2, stats, g1, b1, A, N);
    {
        int waves = (N + 1) / 2;
        spmm_k<32><<<(waves + 3) / 4, 256, 0, stream>>>(rp, ecol, ev, A, B, N);
    }
    stats_k<32><<<512, 256, 0, stream>>>(B, stats + 128, N);

    // layer 3
    gemm_k<32, 16, true><<<gblocks, 256, 0, stream>>>(B, W3, stats + 128, g2, b2, A, N);
    {
        int waves = (N + 3) / 4;
        spmm_k<16><<<(waves + 3) / 4, 256, 0, stream>>>(rp, ecol, ev, A, B, N);
    }
    stats_k<16><<<512, 256, 0, stream>>>(B, stats + 192, N);

    // layer 4 + fused log_softmax
    gemm_k<16, 40, true><<<gblocks, 256, 0, stream>>>(B, W4, stats + 192, g3, b3, A, N);
    spmm4_k<<<(N + 3) / 4, 256, 0, stream>>>(rp, ecol, ev, A, outp, N);
}

// Round 3
// 835.015 us; speedup vs baseline: 1.6505x; 1.0107x over previous
//
#include <hip/hip_runtime.h>
#include <hip/hip_bf16.h>
#include <math.h>

typedef __attribute__((ext_vector_type(8))) short short8;
typedef __attribute__((ext_vector_type(4))) float floatx4;

// ---------------- row_ptr: lower_bound per node over sorted edge_row ----------------
__global__ void rowptr_k(const int* __restrict__ erow, int* __restrict__ rp, int n, int e) {
    int i = blockIdx.x * blockDim.x + threadIdx.x;
    if (i > n) return;
    int lo = 0, hi = e;
    while (lo < hi) {
        int mid = (lo + hi) >> 1;
        if (erow[mid] < i) lo = mid + 1; else hi = mid;
    }
    rp[i] = lo;
}

__global__ void zero_k(float* __restrict__ p) {
    int i = threadIdx.x;
    if (i < 224) p[i] = 0.f;
}

__device__ __forceinline__ float elu_f(float t) {
    return t > 0.f ? t : expm1f(t);
}

__device__ __forceinline__ unsigned short f2bf(float f) {
    unsigned int u = __float_as_uint(f);
    u = (u + 0x7FFFu + ((u >> 16) & 1u)) >> 16;
    return (unsigned short)u;
}

// ---------------- GEMM1 (MFMA bf16): out[N x 64] = X[N x 512] @ W[512 x 64] ---------
// 128x64 tile per block (4 waves, each 32 rows x 64 cols). fp32 -> bf16 RNE on stage.
// As: row-major [128][72] bf16 (pad 72 -> b128 frag reads are 2-way = free).
// Bs: transposed [n][k] = [64][72] bf16 so B-fragments are contiguous b128 too.
__global__ __launch_bounds__(256) void gemm1_mfma_k(const float* __restrict__ X,
                                                    const float* __restrict__ W,
                                                    float* __restrict__ out, int nrows) {
    __shared__ unsigned short As[128 * 72];
    __shared__ unsigned short Bs[64 * 72];

    const int tid  = threadIdx.x;
    const int lane = tid & 63;
    const int wid  = tid >> 6;        // wave 0..3 -> rows [wid*32, wid*32+32)
    const int lrow = lane & 15;
    const int quad = lane >> 4;
    const int row0 = blockIdx.x * 128;

    floatx4 acc[2][4];
#pragma unroll
    for (int mi = 0; mi < 2; ++mi)
#pragma unroll
        for (int ni = 0; ni < 4; ++ni) acc[mi][ni] = (floatx4){0.f, 0.f, 0.f, 0.f};

    for (int k0 = 0; k0 < 512; k0 += 64) {
        // stage A: 128 rows x 64 k, fp32 -> bf16
#pragma unroll
        for (int idx = tid * 4; idx < 128 * 64; idx += 1024) {
            int r = idx >> 6, k = idx & 63;
            int gr = row0 + r;
            float4 v = make_float4(0.f, 0.f, 0.f, 0.f);
            if (gr < nrows) v = *(const float4*)&X[(long)gr * 512 + k0 + k];
            ushort4 b;
            b.x = f2bf(v.x); b.y = f2bf(v.y); b.z = f2bf(v.z); b.w = f2bf(v.w);
            *(ushort4*)&As[r * 72 + k] = b;
        }
        // stage B transposed: Bs[n][kk] = bf16(W[(k0+kk)*64 + n])
#pragma unroll
        for (int idx = tid; idx < 64 * 64; idx += 256) {
            int kk = idx >> 6, n = idx & 63;
            Bs[n * 72 + kk] = f2bf(W[(long)(k0 + kk) * 64 + n]);
        }
        __syncthreads();

#pragma unroll
        for (int kc = 0; kc < 64; kc += 32) {
            short8 af[2], bf[4];
#pragma unroll
            for (int mi = 0; mi < 2; ++mi)
                af[mi] = *(const short8*)&As[(wid * 32 + mi * 16 + lrow) * 72 + kc + quad * 8];
#pragma unroll
            for (int ni = 0; ni < 4; ++ni)
                bf[ni] = *(const short8*)&Bs[(ni * 16 + lrow) * 72 + kc + quad * 8];
#pragma unroll
            for (int mi = 0; mi < 2; ++mi)
#pragma unroll
                for (int ni = 0; ni < 4; ++ni)
                    acc[mi][ni] = __builtin_amdgcn_mfma_f32_16x16x32_bf16(
                        af[mi], bf[ni], acc[mi][ni], 0, 0, 0);
        }
        __syncthreads();
    }

    // C/D layout: col = lane&15, row = quad*4 + reg  [m89-verified]
#pragma unroll
    for (int mi = 0; mi < 2; ++mi)
#pragma unroll
        for (int r = 0; r < 4; ++r) {
            int gr = row0 + wid * 32 + mi * 16 + quad * 4 + r;
            if (gr < nrows) {
#pragma unroll
                for (int ni = 0; ni < 4; ++ni)
                    out[(long)gr * 64 + ni * 16 + lrow] = acc[mi][ni][r];
            }
        }
}

// ---------------- small tiled fp32 GEMM with fused BN+ELU on input ------------------
template<int K, int NC, bool BN>
__global__ __launch_bounds__(256) void gemm_k(const float* __restrict__ X,
                                              const float* __restrict__ W,
                                              const float* __restrict__ stats,
                                              const float* __restrict__ gamma,
                                              const float* __restrict__ beta,
                                              float* __restrict__ out, int nrows) {
    constexpr int KT = (K < 64) ? K : 64;
    constexpr int S  = KT + 4;
    __shared__ float xs[64 * S];
    __shared__ float ws[KT * NC];
    __shared__ float sc[KT];
    __shared__ float sh[KT];

    const int tid  = threadIdx.x;
    const int c    = tid & 63;
    const int rg   = tid >> 6;
    const int row0 = blockIdx.x * 64;

    if (BN) {
        if (tid < K) {
            float s1 = stats[tid], s2 = stats[K + tid];
            float mean = s1 / (float)nrows;
            float var  = s2 / (float)nrows - mean * mean;
            float rstd = rsqrtf(var + 1e-5f);
            float scl  = gamma[tid] * rstd;
            sc[tid] = scl;
            sh[tid] = beta[tid] - mean * scl;
        }
        __syncthreads();
    }

    float acc[16];
#pragma unroll
    for (int i = 0; i < 16; ++i) acc[i] = 0.f;

    for (int k0 = 0; k0 < K; k0 += KT) {
        for (int idx = tid * 4; idx < 64 * KT; idx += 1024) {
            int r = idx / KT, k = idx - r * KT;
            int gr = row0 + r;
            float4 v = make_float4(0.f, 0.f, 0.f, 0.f);
            if (gr < nrows) v = *(const float4*)&X[(long)gr * K + k0 + k];
            if (BN) {
                v.x = elu_f(v.x * sc[k + 0] + sh[k + 0]);
                v.y = elu_f(v.y * sc[k + 1] + sh[k + 1]);
                v.z = elu_f(v.z * sc[k + 2] + sh[k + 2]);
                v.w = elu_f(v.w * sc[k + 3] + sh[k + 3]);
            }
            *(float4*)&xs[r * S + k] = v;
        }
        for (int idx = tid * 4; idx < KT * NC; idx += 1024) {
            *(float4*)&ws[idx] = *(const float4*)&W[k0 * NC + idx];
        }
        __syncthreads();

        if (c < NC) {
            for (int kk = 0; kk < KT; kk += 4) {
                float w0 = ws[(kk + 0) * NC + c];
                float w1 = ws[(kk + 1) * NC + c];
                float w2 = ws[(kk + 2) * NC + c];
                float w3 = ws[(kk + 3) * NC + c];
#pragma unroll
                for (int i = 0; i < 16; ++i) {
                    const float4 xv = *(const float4*)&xs[(rg * 16 + i) * S + kk];
                    acc[i] += xv.x * w0 + xv.y * w1 + xv.z * w2 + xv.w * w3;
                }
            }
        }
        __syncthreads();
    }

    if (c < NC) {
#pragma unroll
        for (int i = 0; i < 16; ++i) {
            int gr = row0 + rg * 16 + i;
            if (gr < nrows) out[(long)gr * NC + c] = acc[i];
        }
    }
}

// ---------------- SpMM: out[i][c] = sum_{e in row i} val[e] * sup[col[e]][c] --------
template<int F>
__global__ __launch_bounds__(256) void spmm_k(const int* __restrict__ rp,
                                              const int* __restrict__ ecol,
                                              const float* __restrict__ ev,
                                              const float* __restrict__ sup,
                                              float* __restrict__ out, int n) {
    constexpr int NPW = 64 / F;  // nodes per wave
    const int lane = threadIdx.x & 63;
    const int wid  = (blockIdx.x * blockDim.x + threadIdx.x) >> 6;
    const int sub  = lane / F;
    const int c    = lane - sub * F;
    const int node = wid * NPW + sub;
    if (node >= n) return;
    int s = rp[node], e = rp[node + 1];
    if (NPW == 1) {
        s = __builtin_amdgcn_readfirstlane(s);
        e = __builtin_amdgcn_readfirstlane(e);
    }
    const float* __restrict__ supc = sup + c;
    float a0 = 0.f, a1 = 0.f, a2 = 0.f, a3 = 0.f;
    int i = s;
    for (; i + 8 <= e; i += 8) {
        int   k0 = ecol[i + 0], k1 = ecol[i + 1], k2 = ecol[i + 2], k3 = ecol[i + 3];
        int   k4 = ecol[i + 4], k5 = ecol[i + 5], k6 = ecol[i + 6], k7 = ecol[i + 7];
        float v0 = ev[i + 0], v1 = ev[i + 1], v2 = ev[i + 2], v3 = ev[i + 3];
        float v4 = ev[i + 4], v5 = ev[i + 5], v6 = ev[i + 6], v7 = ev[i + 7];
        float g0 = supc[(long)k0 * F], g1 = supc[(long)k1 * F];
        float g2 = supc[(long)k2 * F], g3 = supc[(long)k3 * F];
        float g4 = supc[(long)k4 * F], g5 = supc[(long)k5 * F];
        float g6 = supc[(long)k6 * F], g7 = supc[(long)k7 * F];
        a0 += v0 * g0; a1 += v1 * g1; a2 += v2 * g2; a3 += v3 * g3;
        a0 += v4 * g4; a1 += v5 * g5; a2 += v6 * g6; a3 += v7 * g7;
    }
    for (; i < e; ++i) a0 += ev[i] * supc[(long)ecol[i] * F];
    out[(long)node * F + c] = (a0 + a1) + (a2 + a3);
}

// ---------------- SpMM (F=40) + fused log_softmax -----------------------------------
__global__ __launch_bounds__(256) void spmm4_k(const int* __restrict__ rp,
                                               const int* __restrict__ ecol,
                                               const float* __restrict__ ev,
                                               const float* __restrict__ sup,
                                               float* __restrict__ out, int n) {
    const int lane = threadIdx.x & 63;
    const int node = (blockIdx.x * blockDim.x + threadIdx.x) >> 6;
    const bool valid = (lane < 40) && (node < n);
    float acc = -INFINITY;
    if (node < n) {
        int s = rp[node], e = rp[node + 1];
        s = __builtin_amdgcn_readfirstlane(s);
        e = __builtin_amdgcn_readfirstlane(e);
        if (lane < 40) {
            const float* __restrict__ supc = sup + lane;
            float a0 = 0.f, a1 = 0.f, a2 = 0.f, a3 = 0.f;
            int i = s;
            for (; i + 8 <= e; i += 8) {
                int   k0 = ecol[i + 0], k1 = ecol[i + 1], k2 = ecol[i + 2], k3 = ecol[i + 3];
                int   k4 = ecol[i + 4], k5 = ecol[i + 5], k6 = ecol[i + 6], k7 = ecol[i + 7];
                float v0 = ev[i + 0], v1 = ev[i + 1], v2 = ev[i + 2], v3 = ev[i + 3];
                float v4 = ev[i + 4], v5 = ev[i + 5], v6 = ev[i + 6], v7 = ev[i + 7];
                float g0 = supc[(long)k0 * 40], g1 = supc[(long)k1 * 40];
                float g2 = supc[(long)k2 * 40], g3 = supc[(long)k3 * 40];
                float g4 = supc[(long)k4 * 40], g5 = supc[(long)k5 * 40];
                float g6 = supc[(long)k6 * 40], g7 = supc[(long)k7 * 40];
                a0 += v0 * g0; a1 += v1 * g1; a2 += v2 * g2; a3 += v3 * g3;
                a0 += v4 * g4; a1 += v5 * g5; a2 += v6 * g6; a3 += v7 * g7;
            }
            for (; i < e; ++i) a0 += ev[i] * supc[(long)ecol[i] * 40];
            acc = (a0 + a1) + (a2 + a3);
        }
    }
    float m = acc;
#pragma unroll
    for (int o = 32; o; o >>= 1) m = fmaxf(m, __shfl_xor(m, o, 64));
    float p = valid ? expf(acc - m) : 0.f;
    float ssum = p;
#pragma unroll
    for (int o = 32; o; o >>= 1) ssum += __shfl_xor(ssum, o, 64);
    if (valid) out[(long)node * 40 + lane] = acc - m - logf(ssum);
}

// ---------------- per-feature batch sums (for BN): stats[c]=sum, stats[F+c]=sumsq ---
template<int F>
__global__ __launch_bounds__(256) void stats_k(const float* __restrict__ h,
                                               float* __restrict__ stats, int n) {
    __shared__ float sm1[256];
    __shared__ float sm2[256];
    const int tid = threadIdx.x;
    float s1 = 0.f, s2 = 0.f;
    const long total = (long)n * F;
    for (long idx = (long)blockIdx.x * 256 + tid; idx < total; idx += (long)gridDim.x * 256) {
        float v = h[idx];
        s1 += v;
        s2 += v * v;
    }
    sm1[tid] = s1;
    sm2[tid] = s2;
    __syncthreads();
    if (tid < F) {
#pragma unroll
        for (int j = 1; j < 256 / F; ++j) {
            s1 += sm1[tid + j * F];
            s2 += sm2[tid + j * F];
        }
        atomicAdd(&stats[tid], s1);
        atomicAdd(&stats[F + tid], s2);
    }
}

extern "C" void kernel_launch(void* const* d_in, const int* in_sizes, int n_in,
                              void* d_out, int out_size, void* d_ws, size_t ws_size,
                              hipStream_t stream) {
    const float* x    = (const float*)d_in[0];
    const int*   erow = (const int*)d_in[1];
    const int*   ecol = (const int*)d_in[2];
    const float* ev   = (const float*)d_in[3];
    const float* W1   = (const float*)d_in[4];
    const float* W2   = (const float*)d_in[5];
    const float* W3   = (const float*)d_in[6];
    const float* W4   = (const float*)d_in[7];
    const float* g1   = (const float*)d_in[8];
    const float* b1   = (const float*)d_in[9];
    const float* g2   = (const float*)d_in[10];
    const float* b2   = (const float*)d_in[11];
    const float* g3   = (const float*)d_in[12];
    const float* b3   = (const float*)d_in[13];

    const int N = in_sizes[0] / 512;
    const int E = in_sizes[1];

    // workspace layout: row_ptr | stats(224f, 256 reserved) | A (N*64) | B (N*64)
    char* w = (char*)d_ws;
    int* rp = (int*)w;
    size_t off = (((size_t)(N + 1) * 4) + 255) & ~(size_t)255;
    float* stats = (float*)(w + off);
    float* A = stats + 256;
    float* B = A + (size_t)N * 64;
    float* outp = (float*)d_out;

    const int gblocks = (N + 63) / 64;

    rowptr_k<<<(N + 1 + 255) / 256, 256, 0, stream>>>(erow, rp, N, E);
    zero_k<<<1, 256, 0, stream>>>(stats);

    // layer 1: support = x @ W1 (MFMA bf16) ; h1 = SpMM(support)
    gemm1_mfma_k<<<(N + 127) / 128, 256, 0, stream>>>(x, W1, A, N);
    spmm_k<64><<<(N + 3) / 4, 256, 0, stream>>>(rp, ecol, ev, A, B, N);
    stats_k<64><<<512, 256, 0, stream>>>(B, stats, N);

    // layer 2: support = bn_elu(h1) @ W2 ; h2 = SpMM(support)
    gemm_k<64, 32, true><<<gblocks, 256, 0, stream>>>(B, W2, stats, g1, b1, A, N);
    {
        int waves = (N + 1) / 2;
        spmm_k<32><<<(waves + 3) / 4, 256, 0, stream>>>(rp, ecol, ev, A, B, N);
    }
    stats_k<32><<<512, 256, 0, stream>>>(B, stats + 128, N);

    // layer 3
    gemm_k<32, 16, true><<<gblocks, 256, 0, stream>>>(B, W3, stats + 128, g2, b2, A, N);
    {
        int waves = (N + 3) / 4;
        spmm_k<16><<<(waves + 3) / 4, 256, 0, stream>>>(rp, ecol, ev, A, B, N);
    }
    stats_k<16><<<512, 256, 0, stream>>>(B, stats + 192, N);

    // layer 4 + fused log_softmax
    gemm_k<16, 40, true><<<gblocks, 256, 0, stream>>>(B, W4, stats + 192, g3, b3, A, N);
    spmm4_k<<<(N + 3) / 4, 256, 0, stream>>>(rp, ecol, ev, A, outp, N);
}

// Round 4
// 789.528 us; speedup vs baseline: 1.7456x; 1.0576x over previous
//
#include <hip/hip_runtime.h>
#include <hip/hip_bf16.h>
#include <math.h>

typedef __attribute__((ext_vector_type(8))) short short8;
typedef __attribute__((ext_vector_type(4))) float floatx4;

// ---------------- row_ptr: lower_bound per node over sorted edge_row ----------------
__global__ void rowptr_k(const int* __restrict__ erow, int* __restrict__ rp, int n, int e) {
    int i = blockIdx.x * blockDim.x + threadIdx.x;
    if (i > n) return;
    int lo = 0, hi = e;
    while (lo < hi) {
        int mid = (lo + hi) >> 1;
        if (erow[mid] < i) lo = mid + 1; else hi = mid;
    }
    rp[i] = lo;
}

__global__ void zero_k(float* __restrict__ p) {
    int i = threadIdx.x;
    if (i < 224) p[i] = 0.f;
}

__device__ __forceinline__ float elu_f(float t) {
    return t > 0.f ? t : expm1f(t);
}

__device__ __forceinline__ unsigned short f2bf(float f) {
    unsigned int u = __float_as_uint(f);
    u = (u + 0x7FFFu + ((u >> 16) & 1u)) >> 16;
    return (unsigned short)u;
}

// pack two fp32 -> packed bf16x2 (lo in low half), RNE
__device__ __forceinline__ unsigned int f2bf2(float lo, float hi) {
    unsigned int a = __float_as_uint(lo);
    unsigned int b = __float_as_uint(hi);
    a = (a + 0x7FFFu + ((a >> 16) & 1u)) >> 16;
    b = (b + 0x7FFFu + ((b >> 16) & 1u)) & 0xFFFF0000u;
    return a | b;
}

// ---------------- W1 -> bf16 transposed [n][k] ---------------------------------------
__global__ __launch_bounds__(256) void w1bf_k(const float* __restrict__ W,
                                              unsigned short* __restrict__ Wb) {
    int idx = blockIdx.x * 256 + threadIdx.x;  // 0..32767
    int n = idx >> 9, k = idx & 511;
    Wb[idx] = f2bf(W[(long)k * 64 + n]);
}

// ---------------- GEMM1 (MFMA bf16, streaming, no LDS, no barriers) -----------------
// out[N x 64] = X[N x 512] @ W[512 x 64]. One wave per 16-row m-fragment; wave sweeps
// the full k=512 reading A direct global->reg (rows streamed contiguously) and B from
// the L2-resident bf16 Wb[64][512]. fp32->bf16 RNE in-register.
__global__ __launch_bounds__(256) void gemm1_mfma_k(const float* __restrict__ X,
                                                    const unsigned short* __restrict__ Wb,
                                                    float* __restrict__ out, int nrows) {
    const int lane = threadIdx.x & 63;
    const int wid  = threadIdx.x >> 6;
    const int lrow = lane & 15;
    const int quad = lane >> 4;
    const int m0   = (blockIdx.x * 4 + wid) * 16;
    if (m0 >= nrows) return;  // wave-uniform

    int arow = m0 + lrow;
    if (arow >= nrows) arow = nrows - 1;  // clamp (N%16==0 -> never taken, safety)
    const float* __restrict__ xrow = X + (long)arow * 512 + quad * 8;
    const unsigned short* __restrict__ brow = Wb + lrow * 512 + quad * 8;

    floatx4 acc[4];
#pragma unroll
    for (int ni = 0; ni < 4; ++ni) acc[ni] = (floatx4){0.f, 0.f, 0.f, 0.f};

    float4 ca0 = *(const float4*)(xrow + 0);
    float4 ca1 = *(const float4*)(xrow + 4);
    short8 cb[4];
#pragma unroll
    for (int ni = 0; ni < 4; ++ni) cb[ni] = *(const short8*)(brow + ni * 8192);

#pragma unroll
    for (int kc = 0; kc < 16; ++kc) {
        float4 na0, na1;
        short8 nb[4];
        if (kc < 15) {  // compile-time under full unroll
            const float* xp = xrow + (kc + 1) * 32;
            na0 = *(const float4*)(xp + 0);
            na1 = *(const float4*)(xp + 4);
#pragma unroll
            for (int ni = 0; ni < 4; ++ni)
                nb[ni] = *(const short8*)(brow + ni * 8192 + (kc + 1) * 32);
        }
        union { short8 s; unsigned int u[4]; } af;
        af.u[0] = f2bf2(ca0.x, ca0.y);
        af.u[1] = f2bf2(ca0.z, ca0.w);
        af.u[2] = f2bf2(ca1.x, ca1.y);
        af.u[3] = f2bf2(ca1.z, ca1.w);
#pragma unroll
        for (int ni = 0; ni < 4; ++ni)
            acc[ni] = __builtin_amdgcn_mfma_f32_16x16x32_bf16(af.s, cb[ni], acc[ni], 0, 0, 0);
        if (kc < 15) {
            ca0 = na0; ca1 = na1;
#pragma unroll
            for (int ni = 0; ni < 4; ++ni) cb[ni] = nb[ni];
        }
    }

    // C/D layout: col = lane&15, row = quad*4 + reg  [m89-verified]
#pragma unroll
    for (int r = 0; r < 4; ++r) {
        int gr = m0 + quad * 4 + r;
        if (gr < nrows) {
#pragma unroll
            for (int ni = 0; ni < 4; ++ni)
                out[(long)gr * 64 + ni * 16 + lrow] = acc[ni][r];
        }
    }
}

// ---------------- small tiled fp32 GEMM with fused BN+ELU on input ------------------
template<int K, int NC, bool BN>
__global__ __launch_bounds__(256) void gemm_k(const float* __restrict__ X,
                                              const float* __restrict__ W,
                                              const float* __restrict__ stats,
                                              const float* __restrict__ gamma,
                                              const float* __restrict__ beta,
                                              float* __restrict__ out, int nrows) {
    constexpr int KT = (K < 64) ? K : 64;
    constexpr int S  = KT + 4;
    __shared__ float xs[64 * S];
    __shared__ float ws[KT * NC];
    __shared__ float sc[KT];
    __shared__ float sh[KT];

    const int tid  = threadIdx.x;
    const int c    = tid & 63;
    const int rg   = tid >> 6;
    const int row0 = blockIdx.x * 64;

    if (BN) {
        if (tid < K) {
            float s1 = stats[tid], s2 = stats[K + tid];
            float mean = s1 / (float)nrows;
            float var  = s2 / (float)nrows - mean * mean;
            float rstd = rsqrtf(var + 1e-5f);
            float scl  = gamma[tid] * rstd;
            sc[tid] = scl;
            sh[tid] = beta[tid] - mean * scl;
        }
        __syncthreads();
    }

    float acc[16];
#pragma unroll
    for (int i = 0; i < 16; ++i) acc[i] = 0.f;

    for (int k0 = 0; k0 < K; k0 += KT) {
        for (int idx = tid * 4; idx < 64 * KT; idx += 1024) {
            int r = idx / KT, k = idx - r * KT;
            int gr = row0 + r;
            float4 v = make_float4(0.f, 0.f, 0.f, 0.f);
            if (gr < nrows) v = *(const float4*)&X[(long)gr * K + k0 + k];
            if (BN) {
                v.x = elu_f(v.x * sc[k + 0] + sh[k + 0]);
                v.y = elu_f(v.y * sc[k + 1] + sh[k + 1]);
                v.z = elu_f(v.z * sc[k + 2] + sh[k + 2]);
                v.w = elu_f(v.w * sc[k + 3] + sh[k + 3]);
            }
            *(float4*)&xs[r * S + k] = v;
        }
        for (int idx = tid * 4; idx < KT * NC; idx += 1024) {
            *(float4*)&ws[idx] = *(const float4*)&W[k0 * NC + idx];
        }
        __syncthreads();

        if (c < NC) {
            for (int kk = 0; kk < KT; kk += 4) {
                float w0 = ws[(kk + 0) * NC + c];
                float w1 = ws[(kk + 1) * NC + c];
                float w2 = ws[(kk + 2) * NC + c];
                float w3 = ws[(kk + 3) * NC + c];
#pragma unroll
                for (int i = 0; i < 16; ++i) {
                    const float4 xv = *(const float4*)&xs[(rg * 16 + i) * S + kk];
                    acc[i] += xv.x * w0 + xv.y * w1 + xv.z * w2 + xv.w * w3;
                }
            }
        }
        __syncthreads();
    }

    if (c < NC) {
#pragma unroll
        for (int i = 0; i < 16; ++i) {
            int gr = row0 + rg * 16 + i;
            if (gr < nrows) out[(long)gr * NC + c] = acc[i];
        }
    }
}

// ---------------- SpMM: out[i][c] = sum_{e in row i} val[e] * sup[col[e]][c] --------
template<int F>
__global__ __launch_bounds__(256) void spmm_k(const int* __restrict__ rp,
                                              const int* __restrict__ ecol,
                                              const float* __restrict__ ev,
                                              const float* __restrict__ sup,
                                              float* __restrict__ out, int n) {
    constexpr int NPW = 64 / F;  // nodes per wave
    const int lane = threadIdx.x & 63;
    const int wid  = (blockIdx.x * blockDim.x + threadIdx.x) >> 6;
    const int sub  = lane / F;
    const int c    = lane - sub * F;
    const int node = wid * NPW + sub;
    if (node >= n) return;
    int s = rp[node], e = rp[node + 1];
    if (NPW == 1) {
        s = __builtin_amdgcn_readfirstlane(s);
        e = __builtin_amdgcn_readfirstlane(e);
    }
    const float* __restrict__ supc = sup + c;
    float a0 = 0.f, a1 = 0.f, a2 = 0.f, a3 = 0.f;
    int i = s;
    for (; i + 8 <= e; i += 8) {
        int   k0 = ecol[i + 0], k1 = ecol[i + 1], k2 = ecol[i + 2], k3 = ecol[i + 3];
        int   k4 = ecol[i + 4], k5 = ecol[i + 5], k6 = ecol[i + 6], k7 = ecol[i + 7];
        float v0 = ev[i + 0], v1 = ev[i + 1], v2 = ev[i + 2], v3 = ev[i + 3];
        float v4 = ev[i + 4], v5 = ev[i + 5], v6 = ev[i + 6], v7 = ev[i + 7];
        float g0 = supc[(long)k0 * F], g1 = supc[(long)k1 * F];
        float g2 = supc[(long)k2 * F], g3 = supc[(long)k3 * F];
        float g4 = supc[(long)k4 * F], g5 = supc[(long)k5 * F];
        float g6 = supc[(long)k6 * F], g7 = supc[(long)k7 * F];
        a0 += v0 * g0; a1 += v1 * g1; a2 += v2 * g2; a3 += v3 * g3;
        a0 += v4 * g4; a1 += v5 * g5; a2 += v6 * g6; a3 += v7 * g7;
    }
    for (; i < e; ++i) a0 += ev[i] * supc[(long)ecol[i] * F];
    out[(long)node * F + c] = (a0 + a1) + (a2 + a3);
}

// ---------------- SpMM (F=40) + fused log_softmax -----------------------------------
__global__ __launch_bounds__(256) void spmm4_k(const int* __restrict__ rp,
                                               const int* __restrict__ ecol,
                                               const float* __restrict__ ev,
                                               const float* __restrict__ sup,
                                               float* __restrict__ out, int n) {
    const int lane = threadIdx.x & 63;
    const int node = (blockIdx.x * blockDim.x + threadIdx.x) >> 6;
    const bool valid = (lane < 40) && (node < n);
    float acc = -INFINITY;
    if (node < n) {
        int s = rp[node], e = rp[node + 1];
        s = __builtin_amdgcn_readfirstlane(s);
        e = __builtin_amdgcn_readfirstlane(e);
        if (lane < 40) {
            const float* __restrict__ supc = sup + lane;
            float a0 = 0.f, a1 = 0.f, a2 = 0.f, a3 = 0.f;
            int i = s;
            for (; i + 8 <= e; i += 8) {
                int   k0 = ecol[i + 0], k1 = ecol[i + 1], k2 = ecol[i + 2], k3 = ecol[i + 3];
                int   k4 = ecol[i + 4], k5 = ecol[i + 5], k6 = ecol[i + 6], k7 = ecol[i + 7];
                float v0 = ev[i + 0], v1 = ev[i + 1], v2 = ev[i + 2], v3 = ev[i + 3];
                float v4 = ev[i + 4], v5 = ev[i + 5], v6 = ev[i + 6], v7 = ev[i + 7];
                float g0 = supc[(long)k0 * 40], g1 = supc[(long)k1 * 40];
                float g2 = supc[(long)k2 * 40], g3 = supc[(long)k3 * 40];
                float g4 = supc[(long)k4 * 40], g5 = supc[(long)k5 * 40];
                float g6 = supc[(long)k6 * 40], g7 = supc[(long)k7 * 40];
                a0 += v0 * g0; a1 += v1 * g1; a2 += v2 * g2; a3 += v3 * g3;
                a0 += v4 * g4; a1 += v5 * g5; a2 += v6 * g6; a3 += v7 * g7;
            }
            for (; i < e; ++i) a0 += ev[i] * supc[(long)ecol[i] * 40];
            acc = (a0 + a1) + (a2 + a3);
        }
    }
    float m = acc;
#pragma unroll
    for (int o = 32; o; o >>= 1) m = fmaxf(m, __shfl_xor(m, o, 64));
    float p = valid ? expf(acc - m) : 0.f;
    float ssum = p;
#pragma unroll
    for (int o = 32; o; o >>= 1) ssum += __shfl_xor(ssum, o, 64);
    if (valid) out[(long)node * 40 + lane] = acc - m - logf(ssum);
}

// ---------------- per-feature batch sums (for BN): stats[c]=sum, stats[F+c]=sumsq ---
template<int F>
__global__ __launch_bounds__(256) void stats_k(const float* __restrict__ h,
                                               float* __restrict__ stats, int n) {
    __shared__ float sm1[256];
    __shared__ float sm2[256];
    const int tid = threadIdx.x;
    float s1 = 0.f, s2 = 0.f;
    const long total = (long)n * F;
    for (long idx = (long)blockIdx.x * 256 + tid; idx < total; idx += (long)gridDim.x * 256) {
        float v = h[idx];
        s1 += v;
        s2 += v * v;
    }
    sm1[tid] = s1;
    sm2[tid] = s2;
    __syncthreads();
    if (tid < F) {
#pragma unroll
        for (int j = 1; j < 256 / F; ++j) {
            s1 += sm1[tid + j * F];
            s2 += sm2[tid + j * F];
        }
        atomicAdd(&stats[tid], s1);
        atomicAdd(&stats[F + tid], s2);
    }
}

extern "C" void kernel_launch(void* const* d_in, const int* in_sizes, int n_in,
                              void* d_out, int out_size, void* d_ws, size_t ws_size,
                              hipStream_t stream) {
    const float* x    = (const float*)d_in[0];
    const int*   erow = (const int*)d_in[1];
    const int*   ecol = (const int*)d_in[2];
    const float* ev   = (const float*)d_in[3];
    const float* W1   = (const float*)d_in[4];
    const float* W2   = (const float*)d_in[5];
    const float* W3   = (const float*)d_in[6];
    const float* W4   = (const float*)d_in[7];
    const float* g1   = (const float*)d_in[8];
    const float* b1   = (const float*)d_in[9];
    const float* g2   = (const float*)d_in[10];
    const float* b2   = (const float*)d_in[11];
    const float* g3   = (const float*)d_in[12];
    const float* b3   = (const float*)d_in[13];

    const int N = in_sizes[0] / 512;
    const int E = in_sizes[1];

    // workspace: row_ptr | stats(256f) | A (N*64) | B (N*64) | Wb (64x512 bf16)
    char* w = (char*)d_ws;
    int* rp = (int*)w;
    size_t off = (((size_t)(N + 1) * 4) + 255) & ~(size_t)255;
    float* stats = (float*)(w + off);
    float* A = stats + 256;
    float* B = A + (size_t)N * 64;
    unsigned short* Wb = (unsigned short*)(B + (size_t)N * 64);
    float* outp = (float*)d_out;

    const int gblocks = (N + 63) / 64;

    rowptr_k<<<(N + 1 + 255) / 256, 256, 0, stream>>>(erow, rp, N, E);
    zero_k<<<1, 256, 0, stream>>>(stats);
    w1bf_k<<<128, 256, 0, stream>>>(W1, Wb);

    // layer 1: support = x @ W1 (MFMA bf16, streaming) ; h1 = SpMM(support)
    {
        int mfrags = (N + 15) / 16;
        gemm1_mfma_k<<<(mfrags + 3) / 4, 256, 0, stream>>>(x, Wb, A, N);
    }
    spmm_k<64><<<(N + 3) / 4, 256, 0, stream>>>(rp, ecol, ev, A, B, N);
    stats_k<64><<<512, 256, 0, stream>>>(B, stats, N);

    // layer 2: support = bn_elu(h1) @ W2 ; h2 = SpMM(support)
    gemm_k<64, 32, true><<<gblocks, 256, 0, stream>>>(B, W2, stats, g1, b1, A, N);
    {
        int waves = (N + 1) / 2;
        spmm_k<32><<<(waves + 3) / 4, 256, 0, stream>>>(rp, ecol, ev, A, B, N);
    }
    stats_k<32><<<512, 256, 0, stream>>>(B, stats + 128, N);

    // layer 3
    gemm_k<32, 16, true><<<gblocks, 256, 0, stream>>>(B, W3, stats + 128, g2, b2, A, N);
    {
        int waves = (N + 3) / 4;
        spmm_k<16><<<(waves + 3) / 4, 256, 0, stream>>>(rp, ecol, ev, A, B, N);
    }
    stats_k<16><<<512, 256, 0, stream>>>(B, stats + 192, N);

    // layer 4 + fused log_softmax
    gemm_k<16, 40, true><<<gblocks, 256, 0, stream>>>(B, W4, stats + 192, g3, b3, A, N);
    spmm4_k<<<(N + 3) / 4, 256, 0, stream>>>(rp, ecol, ev, A, outp, N);
}

// Round 5
// 664.873 us; speedup vs baseline: 2.0729x; 1.1875x over previous
//
#include <hip/hip_runtime.h>
#include <hip/hip_bf16.h>
#include <math.h>

typedef __attribute__((ext_vector_type(8))) short short8;
typedef __attribute__((ext_vector_type(4))) float floatx4;

// ---------------- row_ptr: lower_bound per node over sorted edge_row ----------------
__global__ void rowptr_k(const int* __restrict__ erow, int* __restrict__ rp, int n, int e) {
    int i = blockIdx.x * blockDim.x + threadIdx.x;
    if (i > n) return;
    int lo = 0, hi = e;
    while (lo < hi) {
        int mid = (lo + hi) >> 1;
        if (erow[mid] < i) lo = mid + 1; else hi = mid;
    }
    rp[i] = lo;
}

__global__ void zero_k(float* __restrict__ p) {
    int i = threadIdx.x;
    if (i < 224) p[i] = 0.f;
}

__device__ __forceinline__ float elu_f(float t) {
    return t > 0.f ? t : expm1f(t);
}

__device__ __forceinline__ unsigned short f2bf(float f) {
    unsigned int u = __float_as_uint(f);
    u = (u + 0x7FFFu + ((u >> 16) & 1u)) >> 16;
    return (unsigned short)u;
}

// pack two fp32 -> packed bf16x2 (lo in low half), RNE
__device__ __forceinline__ unsigned int f2bf2(float lo, float hi) {
    unsigned int a = __float_as_uint(lo);
    unsigned int b = __float_as_uint(hi);
    a = (a + 0x7FFFu + ((a >> 16) & 1u)) >> 16;
    b = (b + 0x7FFFu + ((b >> 16) & 1u)) & 0xFFFF0000u;
    return a | b;
}

__device__ __forceinline__ float bflo(unsigned int d) { return __uint_as_float(d << 16); }
__device__ __forceinline__ float bfhi(unsigned int d) { return __uint_as_float(d & 0xFFFF0000u); }

// ---------------- W1 -> bf16 transposed [n][k] = [64][512] --------------------------
__global__ __launch_bounds__(256) void w1bf_k(const float* __restrict__ W,
                                              unsigned short* __restrict__ Wb) {
    int idx = blockIdx.x * 256 + threadIdx.x;  // 0..32767
    int n = idx >> 9, k = idx & 511;
    Wb[idx] = f2bf(W[(long)k * 64 + n]);
}

// ---------------- W2/W3/W4 -> bf16 transposed (+zero-pad W4 to 48x32) ---------------
__global__ __launch_bounds__(256) void wsmall_k(const float* __restrict__ W2,
                                                const float* __restrict__ W3,
                                                const float* __restrict__ W4,
                                                unsigned short* __restrict__ Wb2,
                                                unsigned short* __restrict__ Wb3,
                                                unsigned short* __restrict__ Wb4) {
    int idx = blockIdx.x * 256 + threadIdx.x;  // 0..2047
    if (idx < 2048) {  // Wb2: [32][64]
        int n = idx >> 6, k = idx & 63;
        Wb2[idx] = f2bf(W2[(long)k * 32 + n]);
    }
    if (idx < 512) {   // Wb3: [16][32]
        int n = idx >> 5, k = idx & 31;
        Wb3[idx] = f2bf(W3[(long)k * 16 + n]);
    }
    if (idx < 1536) {  // Wb4: [48][32], rows>=40 and k>=16 zero
        int n = idx >> 5, k = idx & 31;
        Wb4[idx] = (n < 40 && k < 16) ? f2bf(W4[(long)k * 40 + n]) : (unsigned short)0;
    }
}

// ---------------- GEMM1 (MFMA bf16, streaming): Abf[N x 64] = X @ W1 ----------------
__global__ __launch_bounds__(256) void gemm1_mfma_k(const float* __restrict__ X,
                                                    const unsigned short* __restrict__ Wb,
                                                    unsigned short* __restrict__ out, int nrows) {
    const int lane = threadIdx.x & 63;
    const int wid  = threadIdx.x >> 6;
    const int lrow = lane & 15;
    const int quad = lane >> 4;
    const int m0   = (blockIdx.x * 4 + wid) * 16;
    if (m0 >= nrows) return;  // wave-uniform

    int arow = m0 + lrow;
    if (arow >= nrows) arow = nrows - 1;
    const float* __restrict__ xrow = X + (long)arow * 512 + quad * 8;
    const unsigned short* __restrict__ brow = Wb + lrow * 512 + quad * 8;

    floatx4 acc[4];
#pragma unroll
    for (int ni = 0; ni < 4; ++ni) acc[ni] = (floatx4){0.f, 0.f, 0.f, 0.f};

    float4 ca0 = *(const float4*)(xrow + 0);
    float4 ca1 = *(const float4*)(xrow + 4);
    short8 cb[4];
#pragma unroll
    for (int ni = 0; ni < 4; ++ni) cb[ni] = *(const short8*)(brow + ni * 8192);

#pragma unroll
    for (int kc = 0; kc < 16; ++kc) {
        float4 na0, na1;
        short8 nb[4];
        if (kc < 15) {
            const float* xp = xrow + (kc + 1) * 32;
            na0 = *(const float4*)(xp + 0);
            na1 = *(const float4*)(xp + 4);
#pragma unroll
            for (int ni = 0; ni < 4; ++ni)
                nb[ni] = *(const short8*)(brow + ni * 8192 + (kc + 1) * 32);
        }
        union { short8 s; unsigned int u[4]; } af;
        af.u[0] = f2bf2(ca0.x, ca0.y);
        af.u[1] = f2bf2(ca0.z, ca0.w);
        af.u[2] = f2bf2(ca1.x, ca1.y);
        af.u[3] = f2bf2(ca1.z, ca1.w);
#pragma unroll
        for (int ni = 0; ni < 4; ++ni)
            acc[ni] = __builtin_amdgcn_mfma_f32_16x16x32_bf16(af.s, cb[ni], acc[ni], 0, 0, 0);
        if (kc < 15) {
            ca0 = na0; ca1 = na1;
#pragma unroll
            for (int ni = 0; ni < 4; ++ni) cb[ni] = nb[ni];
        }
    }

    // C/D layout: col = lane&15, row = quad*4 + reg
#pragma unroll
    for (int r = 0; r < 4; ++r) {
        int gr = m0 + quad * 4 + r;
        if (gr < nrows) {
#pragma unroll
            for (int ni = 0; ni < 4; ++ni)
                out[(long)gr * 64 + ni * 16 + lrow] = f2bf(acc[ni][r]);
        }
    }
}

// ---------------- layers 2-4: streaming MFMA bf16 with fused BN+ELU on input --------
// out[N x NSTR] (bf16) = bn_elu(H[N x K]) @ W[K x NC], Wb transposed [NF*16][KP] bf16.
template<int K, int KP, int NF, int NSTR>
__global__ __launch_bounds__(256) void gemmS_k(const unsigned short* __restrict__ H,
                                               const unsigned short* __restrict__ Wb,
                                               const float* __restrict__ stats,
                                               const float* __restrict__ gamma,
                                               const float* __restrict__ beta,
                                               unsigned short* __restrict__ out,
                                               int nrows) {
    __shared__ __align__(16) float scs[K];
    __shared__ __align__(16) float shs[K];
    const int tid = threadIdx.x;
    if (tid < K) {
        float s1 = stats[tid], s2 = stats[K + tid];
        float mean = s1 / (float)nrows;
        float var  = s2 / (float)nrows - mean * mean;
        float rstd = rsqrtf(var + 1e-5f);
        float scl  = gamma[tid] * rstd;
        scs[tid] = scl;
        shs[tid] = beta[tid] - mean * scl;
    }
    __syncthreads();

    const int lane = tid & 63;
    const int wid  = tid >> 6;
    const int lrow = lane & 15;
    const int quad = lane >> 4;
    const int m0   = (blockIdx.x * 4 + wid) * 16;
    if (m0 >= nrows) return;  // after barrier: safe

    int arow = m0 + lrow;
    if (arow >= nrows) arow = nrows - 1;
    const unsigned short* __restrict__ hrow = H + (long)arow * K;

    floatx4 acc[NF];
#pragma unroll
    for (int ni = 0; ni < NF; ++ni) acc[ni] = (floatx4){0.f, 0.f, 0.f, 0.f};

#pragma unroll
    for (int kc = 0; kc < KP; kc += 32) {
        const int k8 = kc + quad * 8;
        union { short8 s; unsigned int u[4]; } af;
        if (k8 < K) {
            uint4 d = *(const uint4*)(hrow + k8);
            float4 sc0 = *(const float4*)&scs[k8];
            float4 sc1 = *(const float4*)&scs[k8 + 4];
            float4 sh0 = *(const float4*)&shs[k8];
            float4 sh1 = *(const float4*)&shs[k8 + 4];
            float f0 = elu_f(bflo(d.x) * sc0.x + sh0.x);
            float f1 = elu_f(bfhi(d.x) * sc0.y + sh0.y);
            float f2 = elu_f(bflo(d.y) * sc0.z + sh0.z);
            float f3 = elu_f(bfhi(d.y) * sc0.w + sh0.w);
            float f4 = elu_f(bflo(d.z) * sc1.x + sh1.x);
            float f5 = elu_f(bfhi(d.z) * sc1.y + sh1.y);
            float f6 = elu_f(bflo(d.w) * sc1.z + sh1.z);
            float f7 = elu_f(bfhi(d.w) * sc1.w + sh1.w);
            af.u[0] = f2bf2(f0, f1);
            af.u[1] = f2bf2(f2, f3);
            af.u[2] = f2bf2(f4, f5);
            af.u[3] = f2bf2(f6, f7);
        } else {
            af.u[0] = af.u[1] = af.u[2] = af.u[3] = 0u;
        }
#pragma unroll
        for (int ni = 0; ni < NF; ++ni) {
            short8 bf = *(const short8*)&Wb[(ni * 16 + lrow) * KP + k8];
            acc[ni] = __builtin_amdgcn_mfma_f32_16x16x32_bf16(af.s, bf, acc[ni], 0, 0, 0);
        }
    }

#pragma unroll
    for (int r = 0; r < 4; ++r) {
        int gr = m0 + quad * 4 + r;
        if (gr < nrows) {
#pragma unroll
            for (int ni = 0; ni < NF; ++ni)
                out[(long)gr * NSTR + ni * 16 + lrow] = f2bf(acc[ni][r]);
        }
    }
}

// ---------------- SpMM bf16: out[i][c] = sum val * sup[col][c]; 1 node per wave -----
// Wave = G groups x GL lanes; each lane loads 4 bf16 (8 B); G edges per batch, 4
// batches unrolled -> 4 independent gathers in flight; cross-group shuffle reduce.
template<int F>
__global__ __launch_bounds__(256) void spmmb_k(const int* __restrict__ rp,
                                               const int* __restrict__ ecol,
                                               const float* __restrict__ ev,
                                               const unsigned short* __restrict__ sup,
                                               unsigned short* __restrict__ out, int n) {
    constexpr int GL = F / 4;   // lanes per group
    constexpr int G  = 64 / GL; // edges per batch
    const int lane = threadIdx.x & 63;
    const int node = (blockIdx.x * blockDim.x + threadIdx.x) >> 6;
    if (node >= n) return;
    int s = __builtin_amdgcn_readfirstlane(rp[node]);
    int e = __builtin_amdgcn_readfirstlane(rp[node + 1]);
    const int g = lane / GL, p = lane % GL;
    float a0 = 0.f, a1 = 0.f, a2 = 0.f, a3 = 0.f;
    for (int i = s; i < e; i += 4 * G) {
#pragma unroll
        for (int b = 0; b < 4; ++b) {
            int idx = i + b * G + g;
            int cidx = idx < e ? idx : e - 1;  // e>s inside loop -> safe
            int col = ecol[cidx];
            float v = ev[cidx];
            if (idx >= e) v = 0.f;
            uint2 d = *(const uint2*)((const char*)sup + (unsigned long long)col * (F * 2) + p * 8);
            a0 += v * bflo(d.x);
            a1 += v * bfhi(d.x);
            a2 += v * bflo(d.y);
            a3 += v * bfhi(d.y);
        }
    }
#pragma unroll
    for (int o = GL; o < 64; o <<= 1) {
        a0 += __shfl_xor(a0, o, 64);
        a1 += __shfl_xor(a1, o, 64);
        a2 += __shfl_xor(a2, o, 64);
        a3 += __shfl_xor(a3, o, 64);
    }
    if (lane < GL) {
        ushort4 o4;
        o4.x = f2bf(a0); o4.y = f2bf(a1); o4.z = f2bf(a2); o4.w = f2bf(a3);
        *(ushort4*)&out[(long)node * F + p * 4] = o4;
    }
}

// ---------------- SpMM (48-stride bf16 support, 40 valid) + fused log_softmax -------
__global__ __launch_bounds__(256) void spmm4b_k(const int* __restrict__ rp,
                                                const int* __restrict__ ecol,
                                                const float* __restrict__ ev,
                                                const unsigned short* __restrict__ sup,
                                                float* __restrict__ out, int n) {
    const int lane = threadIdx.x & 63;
    const int node = (blockIdx.x * blockDim.x + threadIdx.x) >> 6;
    if (node >= n) return;
    int s = __builtin_amdgcn_readfirstlane(rp[node]);
    int e = __builtin_amdgcn_readfirstlane(rp[node + 1]);
    const int g = lane >> 4, p = lane & 15;
    float a0 = 0.f, a1 = 0.f, a2 = 0.f, a3 = 0.f;
    for (int i = s; i < e; i += 16) {
#pragma unroll
        for (int b = 0; b < 4; ++b) {
            int idx = i + b * 4 + g;
            int cidx = idx < e ? idx : e - 1;
            int col = ecol[cidx];
            float v = ev[cidx];
            if (idx >= e || p >= 12) v = 0.f;
            uint2 d = *(const uint2*)((const char*)sup + (unsigned long long)col * 96 + p * 8);
            a0 += v * bflo(d.x);
            a1 += v * bfhi(d.x);
            a2 += v * bflo(d.y);
            a3 += v * bfhi(d.y);
        }
    }
#pragma unroll
    for (int o = 16; o < 64; o <<= 1) {
        a0 += __shfl_xor(a0, o, 64);
        a1 += __shfl_xor(a1, o, 64);
        a2 += __shfl_xor(a2, o, 64);
        a3 += __shfl_xor(a3, o, 64);
    }
    // lane p holds cols 4p..4p+3; valid cols < 40 -> p < 10
    const bool valid = p < 10;
    float lm = valid ? fmaxf(fmaxf(a0, a1), fmaxf(a2, a3)) : -INFINITY;
#pragma unroll
    for (int o = 1; o < 16; o <<= 1) lm = fmaxf(lm, __shfl_xor(lm, o, 64));
    float ls = valid ? (expf(a0 - lm) + expf(a1 - lm) + expf(a2 - lm) + expf(a3 - lm)) : 0.f;
#pragma unroll
    for (int o = 1; o < 16; o <<= 1) ls += __shfl_xor(ls, o, 64);
    float lse = lm + logf(ls);
    if (lane < 10) {  // group 0 only
        float4 o4 = make_float4(a0 - lse, a1 - lse, a2 - lse, a3 - lse);
        *(float4*)&out[(long)node * 40 + p * 4] = o4;
    }
}

// ---------------- per-feature batch sums from bf16 h --------------------------------
template<int F>
__global__ __launch_bounds__(256) void statsb_k(const unsigned short* __restrict__ h,
                                                float* __restrict__ stats, int n) {
    __shared__ float m1[256], m2[256], m3[256], m4[256];
    const int tid = threadIdx.x;
    const unsigned int* h2 = (const unsigned int*)h;
    const long total = (long)n * F / 2;
    float s1 = 0.f, s2 = 0.f, t1 = 0.f, t2 = 0.f;
    for (long idx = (long)blockIdx.x * 256 + tid; idx < total; idx += (long)gridDim.x * 256) {
        unsigned int d = h2[idx];
        float lo = bflo(d), hi = bfhi(d);
        s1 += lo; s2 += lo * lo;
        t1 += hi; t2 += hi * hi;
    }
    m1[tid] = s1; m2[tid] = s2; m3[tid] = t1; m4[tid] = t2;
    __syncthreads();
    if (tid < F / 2) {
#pragma unroll 4
        for (int j = 1; j < 256 / (F / 2); ++j) {
            s1 += m1[tid + j * (F / 2)];
            s2 += m2[tid + j * (F / 2)];
            t1 += m3[tid + j * (F / 2)];
            t2 += m4[tid + j * (F / 2)];
        }
        atomicAdd(&stats[2 * tid], s1);
        atomicAdd(&stats[2 * tid + 1], t1);
        atomicAdd(&stats[F + 2 * tid], s2);
        atomicAdd(&stats[F + 2 * tid + 1], t2);
    }
}

extern "C" void kernel_launch(void* const* d_in, const int* in_sizes, int n_in,
                              void* d_out, int out_size, void* d_ws, size_t ws_size,
                              hipStream_t stream) {
    const float* x    = (const float*)d_in[0];
    const int*   erow = (const int*)d_in[1];
    const int*   ecol = (const int*)d_in[2];
    const float* ev   = (const float*)d_in[3];
    const float* W1   = (const float*)d_in[4];
    const float* W2   = (const float*)d_in[5];
    const float* W3   = (const float*)d_in[6];
    const float* W4   = (const float*)d_in[7];
    const float* g1   = (const float*)d_in[8];
    const float* b1   = (const float*)d_in[9];
    const float* g2   = (const float*)d_in[10];
    const float* b2   = (const float*)d_in[11];
    const float* g3   = (const float*)d_in[12];
    const float* b3   = (const float*)d_in[13];

    const int N = in_sizes[0] / 512;
    const int E = in_sizes[1];

    // workspace: rp | stats(256f) | Abf (N*64 bf16) | Bbf (N*64 bf16) | Wb1 | Wb2 | Wb3 | Wb4
    char* w = (char*)d_ws;
    int* rp = (int*)w;
    size_t off = (((size_t)(N + 1) * 4) + 255) & ~(size_t)255;
    float* stats = (float*)(w + off);
    unsigned short* Abf = (unsigned short*)(stats + 256);
    unsigned short* Bbf = Abf + (size_t)N * 64;
    unsigned short* Wb1 = Bbf + (size_t)N * 64;
    unsigned short* Wb2 = Wb1 + 64 * 512;
    unsigned short* Wb3 = Wb2 + 32 * 64;
    unsigned short* Wb4 = Wb3 + 16 * 32;
    float* outp = (float*)d_out;

    rowptr_k<<<(N + 1 + 255) / 256, 256, 0, stream>>>(erow, rp, N, E);
    zero_k<<<1, 256, 0, stream>>>(stats);
    w1bf_k<<<128, 256, 0, stream>>>(W1, Wb1);
    wsmall_k<<<8, 256, 0, stream>>>(W2, W3, W4, Wb2, Wb3, Wb4);

    const int mblocks = ((N + 15) / 16 + 3) / 4;
    const int sblocks = (N * 64 + 255) / 256;

    // layer 1
    gemm1_mfma_k<<<mblocks, 256, 0, stream>>>(x, Wb1, Abf, N);
    spmmb_k<64><<<sblocks, 256, 0, stream>>>(rp, ecol, ev, Abf, Bbf, N);
    statsb_k<64><<<512, 256, 0, stream>>>(Bbf, stats, N);

    // layer 2
    gemmS_k<64, 64, 2, 32><<<mblocks, 256, 0, stream>>>(Bbf, Wb2, stats, g1, b1, Abf, N);
    spmmb_k<32><<<sblocks, 256, 0, stream>>>(rp, ecol, ev, Abf, Bbf, N);
    statsb_k<32><<<512, 256, 0, stream>>>(Bbf, stats + 128, N);

    // layer 3
    gemmS_k<32, 32, 1, 16><<<mblocks, 256, 0, stream>>>(Bbf, Wb3, stats + 128, g2, b2, Abf, N);
    spmmb_k<16><<<sblocks, 256, 0, stream>>>(rp, ecol, ev, Abf, Bbf, N);
    statsb_k<16><<<512, 256, 0, stream>>>(Bbf, stats + 192, N);

    // layer 4 + fused log_softmax (support padded to 48-col stride, cols 40..47 = 0)
    gemmS_k<16, 32, 3, 48><<<mblocks, 256, 0, stream>>>(Bbf, Wb4, stats + 192, g3, b3, Abf, N);
    spmm4b_k<<<sblocks, 256, 0, stream>>>(rp, ecol, ev, Abf, outp, N);
}